// Round 3
// baseline (578.412 us; speedup 1.0000x reference)
//
#include <hip/hip_runtime.h>
#include <hip/hip_fp16.h>

#define BSH 6                 // bucket = 64 nodes
#define BSZ (1 << BSH)

// ---------------- small prep kernels ----------------

__global__ void k_zero_deg(int* __restrict__ deg, int N) {
  int i = blockIdx.x * blockDim.x + threadIdx.x;
  if (i < N) deg[i] = 0;
}

__global__ void k_count_deg(const int* __restrict__ col, int E, int* __restrict__ deg) {
  int stride = gridDim.x * blockDim.x;
  for (int i = blockIdx.x * blockDim.x + threadIdx.x; i < E; i += stride)
    atomicAdd(&deg[col[i]], 1);
}

__global__ void k_prep(const int* __restrict__ deg, const float* __restrict__ x,
                       float* __restrict__ dinv, float* __restrict__ xd, int N) {
  int i = blockIdx.x * blockDim.x + threadIdx.x;
  if (i < N) {
    float d = rsqrtf((float)deg[i] + 1.0f);  // +1 self-loop
    dinv[i] = d;
    xd[i] = x[i] * d;
  }
}

// ---------------- prefix-sum (CSR offsets) ----------------

__global__ void k_scan1(const int* __restrict__ deg, int N, int* __restrict__ off,
                        int* __restrict__ bsum) {
  __shared__ int wsum[4];
  int i = blockIdx.x * 256 + threadIdx.x;
  int lane = threadIdx.x & 63, wid = threadIdx.x >> 6;
  int v = (i < N) ? deg[i] : 0;
  int inc = v;
  #pragma unroll
  for (int d = 1; d < 64; d <<= 1) { int t = __shfl_up(inc, d); if (lane >= d) inc += t; }
  if (lane == 63) wsum[wid] = inc;
  __syncthreads();
  if (threadIdx.x == 0) {
    int a = 0;
    for (int w = 0; w < 4; ++w) { int t = wsum[w]; wsum[w] = a; a += t; }
    bsum[blockIdx.x] = a;
  }
  __syncthreads();
  if (i < N) off[i] = inc - v + wsum[wid];  // block-local exclusive
}

__global__ void k_scan2(const int* __restrict__ bsum, int nb, int* __restrict__ boff) {
  __shared__ int wsum[8];
  int lane = threadIdx.x & 63, wid = threadIdx.x >> 6;
  int i = threadIdx.x;
  int v = (i < nb) ? bsum[i] : 0;
  int inc = v;
  #pragma unroll
  for (int d = 1; d < 64; d <<= 1) { int t = __shfl_up(inc, d); if (lane >= d) inc += t; }
  if (lane == 63) wsum[wid] = inc;
  __syncthreads();
  if (threadIdx.x == 0) {
    int a = 0;
    for (int w = 0; w < 8; ++w) { int t = wsum[w]; wsum[w] = a; a += t; }
  }
  __syncthreads();
  if (i < nb) boff[i] = inc - v + wsum[wid];
}

__global__ void k_scan3(int* __restrict__ off, const int* __restrict__ boff, int N, int E) {
  int i = blockIdx.x * 256 + threadIdx.x;
  if (i < N) off[i] = off[i] + boff[blockIdx.x];
  if (i == 0) off[N] = E;
}

// ---------------- two-level edge scatter ----------------

__global__ void k_binit(const int* __restrict__ off, int* __restrict__ bpos, int NB, int N) {
  int b = blockIdx.x * blockDim.x + threadIdx.x;
  if (b < NB) {
    int vn = b << BSH;
    bpos[b] = off[vn < N ? vn : N];
  }
}

// pass A: bin edges by dst bucket; packed entry (src<<BSH)|(dst&(BSZ-1))
__global__ void k_binA(const int* __restrict__ ei, int E,
                       int* __restrict__ bpos, unsigned int* __restrict__ ebuf) {
  int stride = gridDim.x * blockDim.x;
  for (int e = blockIdx.x * blockDim.x + threadIdx.x; e < E; e += stride) {
    int src = ei[e];
    int dst = ei[E + e];
    int slot = atomicAdd(&bpos[dst >> BSH], 1);
    ebuf[slot] = ((unsigned int)src << BSH) | (unsigned int)(dst & (BSZ - 1));
  }
}

// pass B: distribute each bucket's segment into final CSR slots (LDS counters)
__global__ __launch_bounds__(256) void k_binB(const unsigned int* __restrict__ ebuf,
                                              const int* __restrict__ off,
                                              int* __restrict__ csr, int N, int NB) {
  __shared__ int pos_l[BSZ];
  int b = blockIdx.x;
  int t = threadIdx.x;
  int vbase = b << BSH;
  if (t < BSZ) {
    int vn = vbase + t;
    pos_l[t] = off[vn < N ? vn : N];
  }
  __syncthreads();
  int beg = off[vbase < N ? vbase : N];
  int vend = vbase + BSZ;
  int end = off[vend < N ? vend : N];
  for (int i = beg + t; i < end; i += 256) {
    unsigned int e = ebuf[i];
    int d = (int)(e & (BSZ - 1));
    int slot = atomicAdd(&pos_l[d], 1);
    csr[slot] = (int)(e >> BSH);
  }
}

// ---------------- conv1: scalar aggregation ----------------

__global__ void k_agg1(const int* __restrict__ off, const int* __restrict__ csr,
                       const float* __restrict__ xd, const float* __restrict__ dinv,
                       float* __restrict__ s, int N) {
  int v = blockIdx.x * blockDim.x + threadIdx.x;
  if (v >= N) return;
  int beg = off[v], end = off[v + 1];
  float sum = xd[v];  // self-loop: x[v]*dinv[v]
  for (int i = beg; i < end; ++i) sum += xd[csr[i]];
  s[v] = dinv[v] * sum;
}

// ---------------- gemm: ys[v][h] = fp16( dinv[v] * (relu(W2*s[v]+b2) @ W3)[h] ) ----------------

#define GEMM_NODES 64
__global__ __launch_bounds__(256) void k_gemm(
    const float* __restrict__ s, const float* __restrict__ dinv,
    const float* __restrict__ W2, const float* __restrict__ b2,
    const float* __restrict__ W3, __half* __restrict__ ys, int N) {
  __shared__ float h1s[GEMM_NODES * 128];  // 32 KB
  __shared__ float sv[GEMM_NODES];
  __shared__ float dv[GEMM_NODES];
  int base = blockIdx.x * GEMM_NODES;
  int t = threadIdx.x;
  if (t < GEMM_NODES) {
    int v = base + t;
    sv[t] = (v < N) ? s[v] : 0.f;
    dv[t] = (v < N) ? dinv[v] : 0.f;
  }
  __syncthreads();
  for (int idx = t; idx < GEMM_NODES * 128; idx += 256) {
    int nn = idx >> 7, k = idx & 127;
    float h1 = fmaf(W2[k], sv[nn], b2[k]);
    h1s[idx] = h1 > 0.f ? h1 : 0.f;
  }
  __syncthreads();
  int h = t & 127;
  int nbase = (t >> 7) * 32;
  float acc[32];
  #pragma unroll
  for (int n = 0; n < 32; ++n) acc[n] = 0.f;
  for (int k4 = 0; k4 < 32; ++k4) {
    int k = k4 * 4;
    float wa = W3[(k + 0) * 128 + h];
    float wb = W3[(k + 1) * 128 + h];
    float wc = W3[(k + 2) * 128 + h];
    float wd = W3[(k + 3) * 128 + h];
    #pragma unroll
    for (int n = 0; n < 32; ++n) {
      const float4 hv = *(const float4*)&h1s[(nbase + n) * 128 + k];
      float a = acc[n];
      a = fmaf(hv.x, wa, a);
      a = fmaf(hv.y, wb, a);
      a = fmaf(hv.z, wc, a);
      a = fmaf(hv.w, wd, a);
      acc[n] = a;
    }
  }
  #pragma unroll
  for (int n = 0; n < 32; ++n) {
    int v = base + nbase + n;
    if (v < N) ys[(size_t)v * 128 + h] = __float2half_rn(acc[n] * dv[nbase + n]);
  }
}

// ---------------- graph meta: counts via binary search + out init ----------------

__global__ void k_meta(const int* __restrict__ batch, int N, int G,
                       const float* __restrict__ lin_b, int C,
                       float* __restrict__ invcnt, float* __restrict__ out) {
  for (int g = threadIdx.x; g < G; g += blockDim.x) {
    int lo = 0, hi = N;
    while (lo < hi) { int mid = (lo + hi) >> 1; if (batch[mid] < g) lo = mid + 1; else hi = mid; }
    int start = lo;
    lo = 0; hi = N;
    while (lo < hi) { int mid = (lo + hi) >> 1; if (batch[mid] < g + 1) lo = mid + 1; else hi = mid; }
    int cnt = lo - start;
    invcnt[g] = 1.0f / (float)(cnt > 0 ? cnt : 1);
  }
  for (int idx = threadIdx.x; idx < G * C; idx += blockDim.x)
    out[idx] = lin_b[idx % C];  // reset every call; atomics accumulate on top
}

// ---------------- conv2 + relu + project + pooled atomic add ----------------

__global__ __launch_bounds__(256) void k_conv2(
    const __half* __restrict__ ys, const int* __restrict__ off, const int* __restrict__ csr,
    const float* __restrict__ dinv, const float* __restrict__ b3,
    const float* __restrict__ lin_w, const int* __restrict__ batch,
    const float* __restrict__ invcnt, float* __restrict__ out, int N) {
  int wid = threadIdx.x >> 6, lane = threadIdx.x & 63;
  int v = blockIdx.x * 4 + wid;
  if (v >= N) return;
  const __half2* ysh = (const __half2*)ys;  // row stride 64 in half2 units
  int beg = off[v], end = off[v + 1];
  // self term: ys row already scaled by dinv[src]
  float2 a0 = __half22float2(ysh[(size_t)v * 64 + lane]);
  float2 a1 = {0.f, 0.f}, a2 = {0.f, 0.f}, a3 = {0.f, 0.f};
  float2 a4 = {0.f, 0.f}, a5 = {0.f, 0.f}, a6 = {0.f, 0.f}, a7 = {0.f, 0.f};
  for (int c0 = beg; c0 < end; c0 += 64) {
    int m = end - c0; if (m > 64) m = 64;
    int myu = (lane < m) ? csr[c0 + lane] : 0;
    int j = 0;
    for (; j + 8 <= m; j += 8) {
      int u0 = __shfl(myu, j);
      int u1 = __shfl(myu, j + 1);
      int u2 = __shfl(myu, j + 2);
      int u3 = __shfl(myu, j + 3);
      int u4 = __shfl(myu, j + 4);
      int u5 = __shfl(myu, j + 5);
      int u6 = __shfl(myu, j + 6);
      int u7 = __shfl(myu, j + 7);
      float2 t0 = __half22float2(ysh[(size_t)u0 * 64 + lane]);
      float2 t1 = __half22float2(ysh[(size_t)u1 * 64 + lane]);
      float2 t2 = __half22float2(ysh[(size_t)u2 * 64 + lane]);
      float2 t3 = __half22float2(ysh[(size_t)u3 * 64 + lane]);
      float2 t4 = __half22float2(ysh[(size_t)u4 * 64 + lane]);
      float2 t5 = __half22float2(ysh[(size_t)u5 * 64 + lane]);
      float2 t6 = __half22float2(ysh[(size_t)u6 * 64 + lane]);
      float2 t7 = __half22float2(ysh[(size_t)u7 * 64 + lane]);
      a0.x += t0.x; a0.y += t0.y;
      a1.x += t1.x; a1.y += t1.y;
      a2.x += t2.x; a2.y += t2.y;
      a3.x += t3.x; a3.y += t3.y;
      a4.x += t4.x; a4.y += t4.y;
      a5.x += t5.x; a5.y += t5.y;
      a6.x += t6.x; a6.y += t6.y;
      a7.x += t7.x; a7.y += t7.y;
    }
    for (; j < m; ++j) {
      int u = __shfl(myu, j);
      float2 t = __half22float2(ysh[(size_t)u * 64 + lane]);
      a0.x += t.x; a0.y += t.y;
    }
  }
  a0.x += a1.x; a0.y += a1.y;
  a2.x += a3.x; a2.y += a3.y;
  a4.x += a5.x; a4.y += a5.y;
  a6.x += a7.x; a6.y += a7.y;
  a0.x += a2.x; a0.y += a2.y;
  a4.x += a6.x; a4.y += a6.y;
  float accx = a0.x + a4.x;
  float accy = a0.y + a4.y;
  float dv = dinv[v];
  float h2a = fmaf(accx, dv, b3[lane * 2 + 0]); h2a = h2a > 0.f ? h2a : 0.f;
  float h2b = fmaf(accy, dv, b3[lane * 2 + 1]); h2b = h2b > 0.f ? h2b : 0.f;
  // project to 16 classes
  float z[16];
  const float* lwa = lin_w + (lane * 2 + 0) * 16;
  const float* lwb = lin_w + (lane * 2 + 1) * 16;
  #pragma unroll
  for (int c = 0; c < 16; ++c) z[c] = h2a * lwa[c] + h2b * lwb[c];
  #pragma unroll
  for (int d = 32; d > 0; d >>= 1) {
    #pragma unroll
    for (int c = 0; c < 16; ++c) z[c] += __shfl_xor(z[c], d);
  }
  int g = batch[v];
  float ic = invcnt[g];
  if (lane < 16) atomicAdd(&out[g * 16 + lane], z[lane] * ic);
}

// ---------------- launch ----------------

extern "C" void kernel_launch(void* const* d_in, const int* in_sizes, int n_in,
                              void* d_out, int out_size, void* d_ws, size_t ws_size,
                              hipStream_t stream) {
  const float* x = (const float*)d_in[0];
  const int* ei = (const int*)d_in[1];      // int32
  const int* batch = (const int*)d_in[2];   // int32
  const float* W2 = (const float*)d_in[4];
  const float* b2 = (const float*)d_in[5];
  const float* W3 = (const float*)d_in[6];
  const float* b3 = (const float*)d_in[7];
  const float* lin_w = (const float*)d_in[8];
  const float* lin_b = (const float*)d_in[9];
  float* out = (float*)d_out;

  int N = in_sizes[0];       // 100000
  int E = in_sizes[1] / 2;   // 1600000
  int C = in_sizes[9];       // 16
  int G = out_size / C;      // 512
  int NB = (N + BSZ - 1) >> BSH;  // 1563 buckets

  char* p = (char*)d_ws;
  auto take = [&](size_t bytes) {
    char* r = p;
    p += (bytes + 255) & ~(size_t)255;
    return r;
  };
  int* deg = (int*)take((size_t)N * 4);
  int* off = (int*)take((size_t)(N + 1) * 4);
  int* bsum = (int*)take(4096);
  int* boff = (int*)take(4096);
  int* bpos = (int*)take((size_t)NB * 4);
  float* dinv = (float*)take((size_t)N * 4);
  float* xd = (float*)take((size_t)N * 4);
  float* s = (float*)take((size_t)N * 4);
  float* invcnt = (float*)take((size_t)G * 4);
  unsigned int* ebuf = (unsigned int*)take((size_t)E * 4);
  int* csr = (int*)take((size_t)E * 4);
  __half* ys = (__half*)take((size_t)N * 128 * 2);  // fp16 intermediate, 25.6 MB

  int nb = (N + 255) / 256;  // 391 (fits k_scan2's 512 threads)

  hipLaunchKernelGGL(k_zero_deg, dim3((N + 255) / 256), dim3(256), 0, stream, deg, N);
  hipLaunchKernelGGL(k_count_deg, dim3(2048), dim3(256), 0, stream, ei + E, E, deg);
  hipLaunchKernelGGL(k_prep, dim3((N + 255) / 256), dim3(256), 0, stream, deg, x, dinv, xd, N);
  hipLaunchKernelGGL(k_scan1, dim3(nb), dim3(256), 0, stream, deg, N, off, bsum);
  hipLaunchKernelGGL(k_scan2, dim3(1), dim3(512), 0, stream, bsum, nb, boff);
  hipLaunchKernelGGL(k_scan3, dim3(nb), dim3(256), 0, stream, off, boff, N, E);
  hipLaunchKernelGGL(k_binit, dim3((NB + 255) / 256), dim3(256), 0, stream, off, bpos, NB, N);
  hipLaunchKernelGGL(k_binA, dim3(2048), dim3(256), 0, stream, ei, E, bpos, ebuf);
  hipLaunchKernelGGL(k_binB, dim3(NB), dim3(256), 0, stream, ebuf, off, csr, N, NB);
  hipLaunchKernelGGL(k_agg1, dim3((N + 255) / 256), dim3(256), 0, stream, off, csr, xd, dinv, s, N);
  hipLaunchKernelGGL(k_gemm, dim3((N + GEMM_NODES - 1) / GEMM_NODES), dim3(256), 0, stream,
                     s, dinv, W2, b2, W3, ys, N);
  hipLaunchKernelGGL(k_meta, dim3(1), dim3(512), 0, stream, batch, N, G, lin_b, C, invcnt, out);
  hipLaunchKernelGGL(k_conv2, dim3((N + 3) / 4), dim3(256), 0, stream,
                     ys, off, csr, dinv, b3, lin_w, batch, invcnt, out, N);
}

// Round 4
// 311.752 us; speedup vs baseline: 1.8554x; 1.8554x over previous
//
#include <hip/hip_runtime.h>
#include <hip/hip_fp16.h>

#define BSH 9                  // bucket = 512 nodes
#define BSZ (1 << BSH)
#define NBX 256                // max buckets supported (N <= 131072)
#define CHUNK 4096             // edges per binning block

// ---------------- zero bucket counters ----------------

__global__ void k_zero_arr(int* __restrict__ a, int n) {
  int i = blockIdx.x * blockDim.x + threadIdx.x;
  if (i < n) a[i] = 0;
}

// ---------------- pass 0: bucket histogram (block-local LDS) ----------------

__global__ __launch_bounds__(256) void k_bcount(const int* __restrict__ ei, int E, int NB,
                                                int* __restrict__ bcnt) {
  __shared__ int cnt_l[NBX];
  for (int b = threadIdx.x; b < NB; b += 256) cnt_l[b] = 0;
  __syncthreads();
  int beg = blockIdx.x * CHUNK;
  int end = beg + CHUNK; if (end > E) end = E;
  for (int i = beg + threadIdx.x; i < end; i += 256)
    atomicAdd(&cnt_l[ei[E + i] >> BSH], 1);
  __syncthreads();
  for (int b = threadIdx.x; b < NB; b += 256) {
    int c = cnt_l[b];
    if (c) atomicAdd(&bcnt[b], c);
  }
}

// ---------------- pass 1: scan bucket counts -> segment bases ----------------

__global__ void k_bscan(const int* __restrict__ bcnt, int NB, int E,
                        int* __restrict__ bbase, int* __restrict__ bpos) {
  int lane = threadIdx.x;  // 64 threads
  int carry = 0;
  for (int g = 0; g * 64 < NB; ++g) {
    int idx = g * 64 + lane;
    int v = (idx < NB) ? bcnt[idx] : 0;
    int inc = v;
    #pragma unroll
    for (int d = 1; d < 64; d <<= 1) { int t = __shfl_up(inc, d); if (lane >= d) inc += t; }
    if (idx < NB) {
      int e = carry + inc - v;
      bbase[idx] = e;
      bpos[idx] = e;
    }
    carry += __shfl(inc, 63);
  }
  if (lane == 0) bbase[NB] = E;
}

// ---------------- pass 2: stage-sorted binning (1 atomic per block-bucket) ----------------

__global__ __launch_bounds__(256) void k_binA(const int* __restrict__ ei, int E, int NB,
                                              int* __restrict__ bpos,
                                              unsigned int* __restrict__ ebuf) {
  __shared__ unsigned int stage[CHUNK];      // 16 KB
  __shared__ unsigned short bid[CHUNK];      // 8 KB
  __shared__ int cnt_l[NBX], start_l[NBX], gbase_l[NBX];
  int t = threadIdx.x;
  int beg = blockIdx.x * CHUNK;
  int end = beg + CHUNK; if (end > E) end = E;
  int n = end - beg;
  for (int b = t; b < NB; b += 256) cnt_l[b] = 0;
  __syncthreads();
  for (int i = t; i < n; i += 256)
    atomicAdd(&cnt_l[ei[E + beg + i] >> BSH], 1);
  __syncthreads();
  if (t < 64) {  // wave 0: exclusive scan of cnt_l[0..NB)
    int carry = 0;
    for (int g = 0; g * 64 < NB; ++g) {
      int idx = g * 64 + t;
      int v = (idx < NB) ? cnt_l[idx] : 0;
      int inc = v;
      #pragma unroll
      for (int d = 1; d < 64; d <<= 1) { int tt = __shfl_up(inc, d); if (t >= d) inc += tt; }
      if (idx < NB) start_l[idx] = carry + inc - v;
      carry += __shfl(inc, 63);
    }
  }
  __syncthreads();
  for (int b = t; b < NB; b += 256) {
    int c = cnt_l[b];
    if (c) gbase_l[b] = atomicAdd(&bpos[b], c);
    cnt_l[b] = 0;
  }
  __syncthreads();
  for (int i = t; i < n; i += 256) {
    int src = ei[beg + i];
    int dst = ei[E + beg + i];
    int b = dst >> BSH;
    int sl = atomicAdd(&cnt_l[b], 1);
    int p = start_l[b] + sl;
    stage[p] = ((unsigned int)src << BSH) | (unsigned int)(dst & (BSZ - 1));
    bid[p] = (unsigned short)b;
  }
  __syncthreads();
  for (int i = t; i < n; i += 256) {
    int b = bid[i];
    ebuf[gbase_l[b] + (i - start_l[b])] = stage[i];
  }
}

// ---------------- pass 3: per-bucket CSR + deg/off/dinv/xd (fused) ----------------

__global__ __launch_bounds__(256) void k_binB(const unsigned int* __restrict__ ebuf,
                                              const int* __restrict__ bbase,
                                              const float* __restrict__ x,
                                              int* __restrict__ off, float* __restrict__ dinv,
                                              float* __restrict__ xd, int* __restrict__ csr,
                                              int N, int E, int NB) {
  __shared__ int degl[BSZ];
  __shared__ int posl[BSZ];
  int b = blockIdx.x;
  int t = threadIdx.x;
  int vbase = b << BSH;
  int seg_beg = bbase[b], seg_end = bbase[b + 1];
  for (int i = t; i < BSZ; i += 256) degl[i] = 0;
  __syncthreads();
  for (int i = seg_beg + t; i < seg_end; i += 256)
    atomicAdd(&degl[ebuf[i] & (BSZ - 1)], 1);
  __syncthreads();
  if (t < 64) {  // wave 0: exclusive scan of degl[0..BSZ)
    int carry = 0;
    #pragma unroll
    for (int g = 0; g < BSZ / 64; ++g) {
      int idx = g * 64 + t;
      int v = degl[idx];
      int inc = v;
      #pragma unroll
      for (int d = 1; d < 64; d <<= 1) { int tt = __shfl_up(inc, d); if (t >= d) inc += tt; }
      posl[idx] = seg_beg + carry + inc - v;
      carry += __shfl(inc, 63);
    }
  }
  __syncthreads();
  for (int i = t; i < BSZ; i += 256) {
    int v = vbase + i;
    if (v < N) {
      off[v] = posl[i];
      float dv = rsqrtf((float)degl[i] + 1.0f);
      dinv[v] = dv;
      xd[v] = x[v] * dv;
    }
  }
  if (b == 0 && t == 0) off[N] = E;
  __syncthreads();
  for (int i = seg_beg + t; i < seg_end; i += 256) {
    unsigned int e = ebuf[i];
    int slot = atomicAdd(&posl[e & (BSZ - 1)], 1);
    csr[slot] = (int)(e >> BSH);
  }
}

// ---------------- conv1: scalar aggregation ----------------

__global__ void k_agg1(const int* __restrict__ off, const int* __restrict__ csr,
                       const float* __restrict__ xd, const float* __restrict__ dinv,
                       float* __restrict__ s, int N) {
  int v = blockIdx.x * blockDim.x + threadIdx.x;
  if (v >= N) return;
  int beg = off[v], end = off[v + 1];
  float sum = xd[v];  // self-loop: x[v]*dinv[v]
  for (int i = beg; i < end; ++i) sum += xd[csr[i]];
  s[v] = dinv[v] * sum;
}

// ---------------- gemm: ys[v][h] = fp16( dinv[v] * (relu(W2*s[v]+b2) @ W3)[h] ) ----------------

#define GEMM_NODES 64
__global__ __launch_bounds__(256) void k_gemm(
    const float* __restrict__ s, const float* __restrict__ dinv,
    const float* __restrict__ W2, const float* __restrict__ b2,
    const float* __restrict__ W3, __half* __restrict__ ys, int N) {
  __shared__ float h1s[GEMM_NODES * 128];  // 32 KB
  __shared__ float sv[GEMM_NODES];
  __shared__ float dv[GEMM_NODES];
  int base = blockIdx.x * GEMM_NODES;
  int t = threadIdx.x;
  if (t < GEMM_NODES) {
    int v = base + t;
    sv[t] = (v < N) ? s[v] : 0.f;
    dv[t] = (v < N) ? dinv[v] : 0.f;
  }
  __syncthreads();
  for (int idx = t; idx < GEMM_NODES * 128; idx += 256) {
    int nn = idx >> 7, k = idx & 127;
    float h1 = fmaf(W2[k], sv[nn], b2[k]);
    h1s[idx] = h1 > 0.f ? h1 : 0.f;
  }
  __syncthreads();
  int h = t & 127;
  int nbase = (t >> 7) * 32;
  float acc[32];
  #pragma unroll
  for (int n = 0; n < 32; ++n) acc[n] = 0.f;
  for (int k4 = 0; k4 < 32; ++k4) {
    int k = k4 * 4;
    float wa = W3[(k + 0) * 128 + h];
    float wb = W3[(k + 1) * 128 + h];
    float wc = W3[(k + 2) * 128 + h];
    float wd = W3[(k + 3) * 128 + h];
    #pragma unroll
    for (int n = 0; n < 32; ++n) {
      const float4 hv = *(const float4*)&h1s[(nbase + n) * 128 + k];
      float a = acc[n];
      a = fmaf(hv.x, wa, a);
      a = fmaf(hv.y, wb, a);
      a = fmaf(hv.z, wc, a);
      a = fmaf(hv.w, wd, a);
      acc[n] = a;
    }
  }
  #pragma unroll
  for (int n = 0; n < 32; ++n) {
    int v = base + nbase + n;
    if (v < N) ys[(size_t)v * 128 + h] = __float2half_rn(acc[n] * dv[nbase + n]);
  }
}

// ---------------- graph meta: counts via binary search + out init ----------------

__global__ void k_meta(const int* __restrict__ batch, int N, int G,
                       const float* __restrict__ lin_b, int C,
                       float* __restrict__ invcnt, float* __restrict__ out) {
  for (int g = threadIdx.x; g < G; g += blockDim.x) {
    int lo = 0, hi = N;
    while (lo < hi) { int mid = (lo + hi) >> 1; if (batch[mid] < g) lo = mid + 1; else hi = mid; }
    int start = lo;
    lo = 0; hi = N;
    while (lo < hi) { int mid = (lo + hi) >> 1; if (batch[mid] < g + 1) lo = mid + 1; else hi = mid; }
    int cnt = lo - start;
    invcnt[g] = 1.0f / (float)(cnt > 0 ? cnt : 1);
  }
  for (int idx = threadIdx.x; idx < G * C; idx += blockDim.x)
    out[idx] = lin_b[idx % C];  // reset every call; atomics accumulate on top
}

// ---------------- conv2 + relu + project + pooled atomic add ----------------

__global__ __launch_bounds__(256) void k_conv2(
    const __half* __restrict__ ys, const int* __restrict__ off, const int* __restrict__ csr,
    const float* __restrict__ dinv, const float* __restrict__ b3,
    const float* __restrict__ lin_w, const int* __restrict__ batch,
    const float* __restrict__ invcnt, float* __restrict__ out, int N) {
  int wid = threadIdx.x >> 6, lane = threadIdx.x & 63;
  int v = blockIdx.x * 4 + wid;
  if (v >= N) return;
  const __half2* ysh = (const __half2*)ys;  // row stride 64 in half2 units
  int beg = off[v], end = off[v + 1];
  // self term: ys row already scaled by dinv[src]
  float2 a0 = __half22float2(ysh[(size_t)v * 64 + lane]);
  float2 a1 = {0.f, 0.f}, a2 = {0.f, 0.f}, a3 = {0.f, 0.f};
  float2 a4 = {0.f, 0.f}, a5 = {0.f, 0.f}, a6 = {0.f, 0.f}, a7 = {0.f, 0.f};
  for (int c0 = beg; c0 < end; c0 += 64) {
    int m = end - c0; if (m > 64) m = 64;
    int myu = (lane < m) ? csr[c0 + lane] : 0;
    int j = 0;
    for (; j + 8 <= m; j += 8) {
      int u0 = __shfl(myu, j);
      int u1 = __shfl(myu, j + 1);
      int u2 = __shfl(myu, j + 2);
      int u3 = __shfl(myu, j + 3);
      int u4 = __shfl(myu, j + 4);
      int u5 = __shfl(myu, j + 5);
      int u6 = __shfl(myu, j + 6);
      int u7 = __shfl(myu, j + 7);
      float2 t0 = __half22float2(ysh[(size_t)u0 * 64 + lane]);
      float2 t1 = __half22float2(ysh[(size_t)u1 * 64 + lane]);
      float2 t2 = __half22float2(ysh[(size_t)u2 * 64 + lane]);
      float2 t3 = __half22float2(ysh[(size_t)u3 * 64 + lane]);
      float2 t4 = __half22float2(ysh[(size_t)u4 * 64 + lane]);
      float2 t5 = __half22float2(ysh[(size_t)u5 * 64 + lane]);
      float2 t6 = __half22float2(ysh[(size_t)u6 * 64 + lane]);
      float2 t7 = __half22float2(ysh[(size_t)u7 * 64 + lane]);
      a0.x += t0.x; a0.y += t0.y;
      a1.x += t1.x; a1.y += t1.y;
      a2.x += t2.x; a2.y += t2.y;
      a3.x += t3.x; a3.y += t3.y;
      a4.x += t4.x; a4.y += t4.y;
      a5.x += t5.x; a5.y += t5.y;
      a6.x += t6.x; a6.y += t6.y;
      a7.x += t7.x; a7.y += t7.y;
    }
    for (; j < m; ++j) {
      int u = __shfl(myu, j);
      float2 t = __half22float2(ysh[(size_t)u * 64 + lane]);
      a0.x += t.x; a0.y += t.y;
    }
  }
  a0.x += a1.x; a0.y += a1.y;
  a2.x += a3.x; a2.y += a3.y;
  a4.x += a5.x; a4.y += a5.y;
  a6.x += a7.x; a6.y += a7.y;
  a0.x += a2.x; a0.y += a2.y;
  a4.x += a6.x; a4.y += a6.y;
  float accx = a0.x + a4.x;
  float accy = a0.y + a4.y;
  float dv = dinv[v];
  float h2a = fmaf(accx, dv, b3[lane * 2 + 0]); h2a = h2a > 0.f ? h2a : 0.f;
  float h2b = fmaf(accy, dv, b3[lane * 2 + 1]); h2b = h2b > 0.f ? h2b : 0.f;
  // project to 16 classes
  float z[16];
  const float* lwa = lin_w + (lane * 2 + 0) * 16;
  const float* lwb = lin_w + (lane * 2 + 1) * 16;
  #pragma unroll
  for (int c = 0; c < 16; ++c) z[c] = h2a * lwa[c] + h2b * lwb[c];
  #pragma unroll
  for (int d = 32; d > 0; d >>= 1) {
    #pragma unroll
    for (int c = 0; c < 16; ++c) z[c] += __shfl_xor(z[c], d);
  }
  int g = batch[v];
  float ic = invcnt[g];
  if (lane < 16) atomicAdd(&out[g * 16 + lane], z[lane] * ic);
}

// ---------------- launch ----------------

extern "C" void kernel_launch(void* const* d_in, const int* in_sizes, int n_in,
                              void* d_out, int out_size, void* d_ws, size_t ws_size,
                              hipStream_t stream) {
  const float* x = (const float*)d_in[0];
  const int* ei = (const int*)d_in[1];      // int32
  const int* batch = (const int*)d_in[2];   // int32
  const float* W2 = (const float*)d_in[4];
  const float* b2 = (const float*)d_in[5];
  const float* W3 = (const float*)d_in[6];
  const float* b3 = (const float*)d_in[7];
  const float* lin_w = (const float*)d_in[8];
  const float* lin_b = (const float*)d_in[9];
  float* out = (float*)d_out;

  int N = in_sizes[0];       // 100000
  int E = in_sizes[1] / 2;   // 1600000
  int C = in_sizes[9];       // 16
  int G = out_size / C;      // 512
  int NB = (N + BSZ - 1) >> BSH;  // 196 buckets

  char* p = (char*)d_ws;
  auto take = [&](size_t bytes) {
    char* r = p;
    p += (bytes + 255) & ~(size_t)255;
    return r;
  };
  int* bcnt = (int*)take((size_t)NB * 4);
  int* bbase = (int*)take((size_t)(NB + 1) * 4);
  int* bpos = (int*)take((size_t)NB * 4);
  int* off = (int*)take((size_t)(N + 1) * 4);
  float* dinv = (float*)take((size_t)N * 4);
  float* xd = (float*)take((size_t)N * 4);
  float* s = (float*)take((size_t)N * 4);
  float* invcnt = (float*)take((size_t)G * 4);
  unsigned int* ebuf = (unsigned int*)take((size_t)E * 4);
  int* csr = (int*)take((size_t)E * 4);
  __half* ys = (__half*)take((size_t)N * 128 * 2);  // fp16 intermediate, 25.6 MB

  int nchunks = (E + CHUNK - 1) / CHUNK;  // 391

  hipLaunchKernelGGL(k_zero_arr, dim3((NB + 255) / 256), dim3(256), 0, stream, bcnt, NB);
  hipLaunchKernelGGL(k_bcount, dim3(nchunks), dim3(256), 0, stream, ei, E, NB, bcnt);
  hipLaunchKernelGGL(k_bscan, dim3(1), dim3(64), 0, stream, bcnt, NB, E, bbase, bpos);
  hipLaunchKernelGGL(k_binA, dim3(nchunks), dim3(256), 0, stream, ei, E, NB, bpos, ebuf);
  hipLaunchKernelGGL(k_binB, dim3(NB), dim3(256), 0, stream, ebuf, bbase, x,
                     off, dinv, xd, csr, N, E, NB);
  hipLaunchKernelGGL(k_agg1, dim3((N + 255) / 256), dim3(256), 0, stream, off, csr, xd, dinv, s, N);
  hipLaunchKernelGGL(k_gemm, dim3((N + GEMM_NODES - 1) / GEMM_NODES), dim3(256), 0, stream,
                     s, dinv, W2, b2, W3, ys, N);
  hipLaunchKernelGGL(k_meta, dim3(1), dim3(512), 0, stream, batch, N, G, lin_b, C, invcnt, out);
  hipLaunchKernelGGL(k_conv2, dim3((N + 3) / 4), dim3(256), 0, stream,
                     ys, off, csr, dinv, b3, lin_w, batch, invcnt, out, N);
}

// Round 5
// 300.929 us; speedup vs baseline: 1.9221x; 1.0360x over previous
//
#include <hip/hip_runtime.h>
#include <hip/hip_fp16.h>

#define BSH 9                  // bucket = 512 nodes
#define BSZ (1 << BSH)
#define NBX 256                // max buckets supported (N <= 131072)
#define CHUNK 4096             // edges per binning block

// ---------------- zero bucket counters ----------------

__global__ void k_zero_arr(int* __restrict__ a, int n) {
  int i = blockIdx.x * blockDim.x + threadIdx.x;
  if (i < n) a[i] = 0;
}

// ---------------- pass 0: bucket histogram (block-local LDS) ----------------

__global__ __launch_bounds__(256) void k_bcount(const int* __restrict__ ei, int E, int NB,
                                                int* __restrict__ bcnt) {
  __shared__ int cnt_l[NBX];
  for (int b = threadIdx.x; b < NB; b += 256) cnt_l[b] = 0;
  __syncthreads();
  int beg = blockIdx.x * CHUNK;
  int end = beg + CHUNK; if (end > E) end = E;
  for (int i = beg + threadIdx.x; i < end; i += 256)
    atomicAdd(&cnt_l[ei[E + i] >> BSH], 1);
  __syncthreads();
  for (int b = threadIdx.x; b < NB; b += 256) {
    int c = cnt_l[b];
    if (c) atomicAdd(&bcnt[b], c);
  }
}

// ---------------- pass 1: scan bucket counts -> segment bases ----------------

__global__ void k_bscan(const int* __restrict__ bcnt, int NB, int E,
                        int* __restrict__ bbase, int* __restrict__ bpos) {
  int lane = threadIdx.x;  // 64 threads
  int carry = 0;
  for (int g = 0; g * 64 < NB; ++g) {
    int idx = g * 64 + lane;
    int v = (idx < NB) ? bcnt[idx] : 0;
    int inc = v;
    #pragma unroll
    for (int d = 1; d < 64; d <<= 1) { int t = __shfl_up(inc, d); if (lane >= d) inc += t; }
    if (idx < NB) {
      int e = carry + inc - v;
      bbase[idx] = e;
      bpos[idx] = e;
    }
    carry += __shfl(inc, 63);
  }
  if (lane == 0) bbase[NB] = E;
}

// ---------------- pass 2: stage-sorted binning (1 atomic per block-bucket) ----------------

__global__ __launch_bounds__(256) void k_binA(const int* __restrict__ ei, int E, int NB,
                                              int* __restrict__ bpos,
                                              unsigned int* __restrict__ ebuf) {
  __shared__ unsigned int stage[CHUNK];      // 16 KB
  __shared__ unsigned short bid[CHUNK];      // 8 KB
  __shared__ int cnt_l[NBX], start_l[NBX], gbase_l[NBX];
  int t = threadIdx.x;
  int beg = blockIdx.x * CHUNK;
  int end = beg + CHUNK; if (end > E) end = E;
  int n = end - beg;
  for (int b = t; b < NB; b += 256) cnt_l[b] = 0;
  __syncthreads();
  for (int i = t; i < n; i += 256)
    atomicAdd(&cnt_l[ei[E + beg + i] >> BSH], 1);
  __syncthreads();
  if (t < 64) {  // wave 0: exclusive scan of cnt_l[0..NB)
    int carry = 0;
    for (int g = 0; g * 64 < NB; ++g) {
      int idx = g * 64 + t;
      int v = (idx < NB) ? cnt_l[idx] : 0;
      int inc = v;
      #pragma unroll
      for (int d = 1; d < 64; d <<= 1) { int tt = __shfl_up(inc, d); if (t >= d) inc += tt; }
      if (idx < NB) start_l[idx] = carry + inc - v;
      carry += __shfl(inc, 63);
    }
  }
  __syncthreads();
  for (int b = t; b < NB; b += 256) {
    int c = cnt_l[b];
    if (c) gbase_l[b] = atomicAdd(&bpos[b], c);
    cnt_l[b] = 0;
  }
  __syncthreads();
  for (int i = t; i < n; i += 256) {
    int src = ei[beg + i];
    int dst = ei[E + beg + i];
    int b = dst >> BSH;
    int sl = atomicAdd(&cnt_l[b], 1);
    int p = start_l[b] + sl;
    stage[p] = ((unsigned int)src << BSH) | (unsigned int)(dst & (BSZ - 1));
    bid[p] = (unsigned short)b;
  }
  __syncthreads();
  for (int i = t; i < n; i += 256) {
    int b = bid[i];
    ebuf[gbase_l[b] + (i - start_l[b])] = stage[i];
  }
}

// ---------------- pass 3: per-bucket CSR + deg/off/dinv/xd (fused) ----------------

__global__ __launch_bounds__(256) void k_binB(const unsigned int* __restrict__ ebuf,
                                              const int* __restrict__ bbase,
                                              const float* __restrict__ x,
                                              int* __restrict__ off, float* __restrict__ dinv,
                                              float* __restrict__ xd, int* __restrict__ csr,
                                              int N, int E, int NB) {
  __shared__ int degl[BSZ];
  __shared__ int posl[BSZ];
  int b = blockIdx.x;
  int t = threadIdx.x;
  int vbase = b << BSH;
  int seg_beg = bbase[b], seg_end = bbase[b + 1];
  for (int i = t; i < BSZ; i += 256) degl[i] = 0;
  __syncthreads();
  for (int i = seg_beg + t; i < seg_end; i += 256)
    atomicAdd(&degl[ebuf[i] & (BSZ - 1)], 1);
  __syncthreads();
  if (t < 64) {  // wave 0: exclusive scan of degl[0..BSZ)
    int carry = 0;
    #pragma unroll
    for (int g = 0; g < BSZ / 64; ++g) {
      int idx = g * 64 + t;
      int v = degl[idx];
      int inc = v;
      #pragma unroll
      for (int d = 1; d < 64; d <<= 1) { int tt = __shfl_up(inc, d); if (t >= d) inc += tt; }
      posl[idx] = seg_beg + carry + inc - v;
      carry += __shfl(inc, 63);
    }
  }
  __syncthreads();
  for (int i = t; i < BSZ; i += 256) {
    int v = vbase + i;
    if (v < N) {
      off[v] = posl[i];
      float dv = rsqrtf((float)degl[i] + 1.0f);
      dinv[v] = dv;
      xd[v] = x[v] * dv;
    }
  }
  if (b == 0 && t == 0) off[N] = E;
  __syncthreads();
  for (int i = seg_beg + t; i < seg_end; i += 256) {
    unsigned int e = ebuf[i];
    int slot = atomicAdd(&posl[e & (BSZ - 1)], 1);
    csr[slot] = (int)(e >> BSH);
  }
}

// ---------------- conv1: scalar aggregation ----------------

__global__ void k_agg1(const int* __restrict__ off, const int* __restrict__ csr,
                       const float* __restrict__ xd, const float* __restrict__ dinv,
                       float* __restrict__ s, int N) {
  int v = blockIdx.x * blockDim.x + threadIdx.x;
  if (v >= N) return;
  int beg = off[v], end = off[v + 1];
  float sum = xd[v];  // self-loop: x[v]*dinv[v]
  for (int i = beg; i < end; ++i) sum += xd[csr[i]];
  s[v] = dinv[v] * sum;
}

// ---------------- gemm: ys[v][h] = fp16( dinv[v] * (relu(W2*s[v]+b2) @ W3)[h] ) ----------------

#define GEMM_NODES 64
__global__ __launch_bounds__(256) void k_gemm(
    const float* __restrict__ s, const float* __restrict__ dinv,
    const float* __restrict__ W2, const float* __restrict__ b2,
    const float* __restrict__ W3, __half* __restrict__ ys, int N) {
  __shared__ float h1s[GEMM_NODES * 128];  // 32 KB
  __shared__ float sv[GEMM_NODES];
  __shared__ float dv[GEMM_NODES];
  int base = blockIdx.x * GEMM_NODES;
  int t = threadIdx.x;
  if (t < GEMM_NODES) {
    int v = base + t;
    sv[t] = (v < N) ? s[v] : 0.f;
    dv[t] = (v < N) ? dinv[v] : 0.f;
  }
  __syncthreads();
  for (int idx = t; idx < GEMM_NODES * 128; idx += 256) {
    int nn = idx >> 7, k = idx & 127;
    float h1 = fmaf(W2[k], sv[nn], b2[k]);
    h1s[idx] = h1 > 0.f ? h1 : 0.f;
  }
  __syncthreads();
  int h = t & 127;
  int nbase = (t >> 7) * 32;
  float acc[32];
  #pragma unroll
  for (int n = 0; n < 32; ++n) acc[n] = 0.f;
  for (int k4 = 0; k4 < 32; ++k4) {
    int k = k4 * 4;
    float wa = W3[(k + 0) * 128 + h];
    float wb = W3[(k + 1) * 128 + h];
    float wc = W3[(k + 2) * 128 + h];
    float wd = W3[(k + 3) * 128 + h];
    #pragma unroll
    for (int n = 0; n < 32; ++n) {
      const float4 hv = *(const float4*)&h1s[(nbase + n) * 128 + k];
      float a = acc[n];
      a = fmaf(hv.x, wa, a);
      a = fmaf(hv.y, wb, a);
      a = fmaf(hv.z, wc, a);
      a = fmaf(hv.w, wd, a);
      acc[n] = a;
    }
  }
  #pragma unroll
  for (int n = 0; n < 32; ++n) {
    int v = base + nbase + n;
    if (v < N) ys[(size_t)v * 128 + h] = __float2half_rn(acc[n] * dv[nbase + n]);
  }
}

// ---------------- graph meta ----------------

__global__ void k_meta(const int* __restrict__ batch, int N, int G,
                       float* __restrict__ invcnt) {
  int g = blockIdx.x * blockDim.x + threadIdx.x;
  if (g >= G) return;
  int lo = 0, hi = N;
  while (lo < hi) { int mid = (lo + hi) >> 1; if (batch[mid] < g) lo = mid + 1; else hi = mid; }
  int start = lo;
  lo = 0; hi = N;
  while (lo < hi) { int mid = (lo + hi) >> 1; if (batch[mid] < g + 1) lo = mid + 1; else hi = mid; }
  int cnt = lo - start;
  invcnt[g] = 1.0f / (float)(cnt > 0 ? cnt : 1);
}

__global__ void k_outinit(const float* __restrict__ lin_b, int C, int GC,
                          float* __restrict__ out) {
  int i = blockIdx.x * blockDim.x + threadIdx.x;
  if (i < GC) out[i] = lin_b[i % C];  // reset every call; atomics accumulate on top
}

// ---------------- conv2 + relu + project + pooled atomic add ----------------

__device__ __forceinline__ void acc8(float* a, uint4 q) {
  const __half2* h = (const __half2*)&q;
  #pragma unroll
  for (int i = 0; i < 4; ++i) {
    float2 f = __half22float2(h[i]);
    a[2 * i] += f.x;
    a[2 * i + 1] += f.y;
  }
}

__global__ __launch_bounds__(256) void k_conv2(
    const __half* __restrict__ ys, const int* __restrict__ off, const int* __restrict__ csr,
    const float* __restrict__ dinv, const float* __restrict__ b3,
    const float* __restrict__ lin_w, const int* __restrict__ batch,
    const float* __restrict__ invcnt, float* __restrict__ out, int N) {
  int wid = threadIdx.x >> 6, lane = threadIdx.x & 63;
  int v = blockIdx.x * 4 + wid;
  if (v >= N) return;
  int g16 = lane >> 4, l16 = lane & 15;
  int beg = off[v], end = off[v + 1];

  float acc[8];
  #pragma unroll
  for (int d = 0; d < 8; ++d) acc[d] = 0.f;

  // each 16-lane group handles one edge per load; lane covers dims l16*8..l16*8+7
  for (int c0 = beg; c0 < end; c0 += 64) {
    int m = end - c0; if (m > 64) m = 64;
    int myu = (lane < m) ? csr[c0 + lane] : 0;
    int j = 0;
    for (; j + 16 <= m; j += 16) {
      int u0 = __shfl(myu, j + g16);
      int u1 = __shfl(myu, j + 4 + g16);
      int u2 = __shfl(myu, j + 8 + g16);
      int u3 = __shfl(myu, j + 12 + g16);
      uint4 q0 = ((const uint4*)(ys + (size_t)u0 * 128))[l16];
      uint4 q1 = ((const uint4*)(ys + (size_t)u1 * 128))[l16];
      uint4 q2 = ((const uint4*)(ys + (size_t)u2 * 128))[l16];
      uint4 q3 = ((const uint4*)(ys + (size_t)u3 * 128))[l16];
      acc8(acc, q0); acc8(acc, q1); acc8(acc, q2); acc8(acc, q3);
    }
    for (; j + 4 <= m; j += 4) {
      int u = __shfl(myu, j + g16);
      uint4 q = ((const uint4*)(ys + (size_t)u * 128))[l16];
      acc8(acc, q);
    }
    int r = m - j;  // 0..3
    if (r > 0) {
      int safe = g16 < r ? g16 : 0;
      int u = __shfl(myu, j + safe);
      if (g16 < r) {
        uint4 q = ((const uint4*)(ys + (size_t)u * 128))[l16];
        acc8(acc, q);
      }
    }
  }

  // combine the 4 sub-groups
  #pragma unroll
  for (int d = 0; d < 8; ++d) {
    acc[d] += __shfl_xor(acc[d], 16);
    acc[d] += __shfl_xor(acc[d], 32);
  }
  // self term (once)
  {
    uint4 qs = ((const uint4*)(ys + (size_t)v * 128))[l16];
    acc8(acc, qs);
  }

  float dv = dinv[v];
  // this group's 4 classes: c = g16*4 + 0..3
  float zc0 = 0.f, zc1 = 0.f, zc2 = 0.f, zc3 = 0.f;
  #pragma unroll
  for (int d = 0; d < 8; ++d) {
    int dim = l16 * 8 + d;
    float h2 = fmaf(acc[d], dv, b3[dim]);
    h2 = h2 > 0.f ? h2 : 0.f;
    float4 w = *(const float4*)(lin_w + dim * 16 + g16 * 4);
    zc0 = fmaf(h2, w.x, zc0);
    zc1 = fmaf(h2, w.y, zc1);
    zc2 = fmaf(h2, w.z, zc2);
    zc3 = fmaf(h2, w.w, zc3);
  }
  // reduce over the 16 lanes of this group
  #pragma unroll
  for (int d = 8; d > 0; d >>= 1) {
    zc0 += __shfl_xor(zc0, d);
    zc1 += __shfl_xor(zc1, d);
    zc2 += __shfl_xor(zc2, d);
    zc3 += __shfl_xor(zc3, d);
  }
  int g = batch[v];
  float ic = invcnt[g];
  if (l16 == 0) atomicAdd(&out[g * 16 + g16 * 4 + 0], zc0 * ic);
  if (l16 == 1) atomicAdd(&out[g * 16 + g16 * 4 + 1], zc1 * ic);
  if (l16 == 2) atomicAdd(&out[g * 16 + g16 * 4 + 2], zc2 * ic);
  if (l16 == 3) atomicAdd(&out[g * 16 + g16 * 4 + 3], zc3 * ic);
}

// ---------------- launch ----------------

extern "C" void kernel_launch(void* const* d_in, const int* in_sizes, int n_in,
                              void* d_out, int out_size, void* d_ws, size_t ws_size,
                              hipStream_t stream) {
  const float* x = (const float*)d_in[0];
  const int* ei = (const int*)d_in[1];      // int32
  const int* batch = (const int*)d_in[2];   // int32
  const float* W2 = (const float*)d_in[4];
  const float* b2 = (const float*)d_in[5];
  const float* W3 = (const float*)d_in[6];
  const float* b3 = (const float*)d_in[7];
  const float* lin_w = (const float*)d_in[8];
  const float* lin_b = (const float*)d_in[9];
  float* out = (float*)d_out;

  int N = in_sizes[0];       // 100000
  int E = in_sizes[1] / 2;   // 1600000
  int C = in_sizes[9];       // 16
  int G = out_size / C;      // 512
  int NB = (N + BSZ - 1) >> BSH;  // 196 buckets

  char* p = (char*)d_ws;
  auto take = [&](size_t bytes) {
    char* r = p;
    p += (bytes + 255) & ~(size_t)255;
    return r;
  };
  int* bcnt = (int*)take((size_t)NB * 4);
  int* bbase = (int*)take((size_t)(NB + 1) * 4);
  int* bpos = (int*)take((size_t)NB * 4);
  int* off = (int*)take((size_t)(N + 1) * 4);
  float* dinv = (float*)take((size_t)N * 4);
  float* xd = (float*)take((size_t)N * 4);
  float* s = (float*)take((size_t)N * 4);
  float* invcnt = (float*)take((size_t)G * 4);
  unsigned int* ebuf = (unsigned int*)take((size_t)E * 4);
  int* csr = (int*)take((size_t)E * 4);
  __half* ys = (__half*)take((size_t)N * 128 * 2);  // fp16 intermediate, 25.6 MB

  int nchunks = (E + CHUNK - 1) / CHUNK;  // 391

  hipLaunchKernelGGL(k_zero_arr, dim3((NB + 255) / 256), dim3(256), 0, stream, bcnt, NB);
  hipLaunchKernelGGL(k_bcount, dim3(nchunks), dim3(256), 0, stream, ei, E, NB, bcnt);
  hipLaunchKernelGGL(k_bscan, dim3(1), dim3(64), 0, stream, bcnt, NB, E, bbase, bpos);
  hipLaunchKernelGGL(k_binA, dim3(nchunks), dim3(256), 0, stream, ei, E, NB, bpos, ebuf);
  hipLaunchKernelGGL(k_binB, dim3(NB), dim3(256), 0, stream, ebuf, bbase, x,
                     off, dinv, xd, csr, N, E, NB);
  hipLaunchKernelGGL(k_agg1, dim3((N + 255) / 256), dim3(256), 0, stream, off, csr, xd, dinv, s, N);
  hipLaunchKernelGGL(k_gemm, dim3((N + GEMM_NODES - 1) / GEMM_NODES), dim3(256), 0, stream,
                     s, dinv, W2, b2, W3, ys, N);
  hipLaunchKernelGGL(k_meta, dim3((G + 255) / 256), dim3(256), 0, stream, batch, N, G, invcnt);
  hipLaunchKernelGGL(k_outinit, dim3((G * C + 255) / 256), dim3(256), 0, stream, lin_b, C, G * C, out);
  hipLaunchKernelGGL(k_conv2, dim3((N + 3) / 4), dim3(256), 0, stream,
                     ys, off, csr, dinv, b3, lin_w, batch, invcnt, out, N);
}